// Round 1
// baseline (358.331 us; speedup 1.0000x reference)
//
#include <hip/hip_runtime.h>
#include <stdint.h>

// Problem constants (fixed by setup_inputs)
#define BB    64
#define NN    4
#define HH    512
#define WW    512
#define HWPIX (HH * WW)        // 262144 pixels per batch
#define WORDS (HWPIX / 64)     // 4096 uint64 words per batch
#define NUM   1024             // samples per batch

// ---------------------------------------------------------------------------
// Kernel 1: valid = (sum over N of mask) > 0.5, packed into uint64 bitmask.
// 256 threads/block, 4 pixels/thread (float4 loads), 256 blocks per batch.
// Sum order is sequential ((m0+m1)+m2)+m3 to match the reference reduction.
// ---------------------------------------------------------------------------
__global__ __launch_bounds__(256) void k_bits(const float* __restrict__ m,
                                              uint64_t* __restrict__ bits) {
    const int bid   = blockIdx.x;
    const int b     = bid >> 8;        // 256 blocks per batch
    const int chunk = bid & 255;       // 1024 pixels per block
    const int tid   = threadIdx.x;     // 0..255
    const int base  = chunk * 1024 + tid * 4;   // pixel index within batch

    const float* p = m + (size_t)b * (NN * HWPIX) + base;
    float4 v0 = *(const float4*)(p);
    float4 v1 = *(const float4*)(p + HWPIX);
    float4 v2 = *(const float4*)(p + 2 * HWPIX);
    float4 v3 = *(const float4*)(p + 3 * HWPIX);

    float s0 = ((v0.x + v1.x) + v2.x) + v3.x;
    float s1 = ((v0.y + v1.y) + v2.y) + v3.y;
    float s2 = ((v0.z + v1.z) + v2.z) + v3.z;
    float s3 = ((v0.w + v1.w) + v2.w) + v3.w;

    unsigned nib = (s0 > 0.5f ? 1u : 0u) | (s1 > 0.5f ? 2u : 0u) |
                   (s2 > 0.5f ? 4u : 0u) | (s3 > 0.5f ? 8u : 0u);

    const int lane = tid & 63;
    // Pixel handled by lane l, sub-pixel k maps to word (chunk*16 + wave*4 + l/16),
    // bit 4*(l&15)+k. Pack nibble, OR-combine across each 16-lane group.
    unsigned long long wv = (unsigned long long)nib << (4 * (lane & 15));
    wv |= __shfl_xor(wv, 1);
    wv |= __shfl_xor(wv, 2);
    wv |= __shfl_xor(wv, 4);
    wv |= __shfl_xor(wv, 8);
    if ((lane & 15) == 0) {
        const int widx = chunk * 16 + (tid >> 6) * 4 + (lane >> 4);
        bits[(size_t)b * WORDS + widx] = wv;
    }
}

// ---------------------------------------------------------------------------
// Kernel 2: per-batch exclusive prefix over per-word popcounts.
// One block of 1024 threads per batch; each thread owns 4 consecutive words.
// prefix layout: [B][WORDS+1]; prefix[w] = #valid pixels in words [0,w).
// ---------------------------------------------------------------------------
__global__ __launch_bounds__(1024) void k_scan(const uint64_t* __restrict__ bits,
                                               int* __restrict__ prefix) {
    const int b   = blockIdx.x;
    const int tid = threadIdx.x;          // 0..1023
    const uint64_t* wb = bits + (size_t)b * WORDS;

    uint64_t w0 = wb[tid * 4 + 0];
    uint64_t w1 = wb[tid * 4 + 1];
    uint64_t w2 = wb[tid * 4 + 2];
    uint64_t w3 = wb[tid * 4 + 3];
    int c0 = __popcll(w0), c1 = __popcll(w1), c2 = __popcll(w2), c3 = __popcll(w3);
    int tot = c0 + c1 + c2 + c3;

    __shared__ int sc[1024];
    sc[tid] = tot;
    __syncthreads();
    // Hillis-Steele inclusive scan
    for (int off = 1; off < 1024; off <<= 1) {
        int v = (tid >= off) ? sc[tid - off] : 0;
        __syncthreads();
        sc[tid] += v;
        __syncthreads();
    }
    const int inclusive = sc[tid];
    const int exclusive = inclusive - tot;

    int* pb = prefix + (size_t)b * (WORDS + 1);
    pb[tid * 4 + 0] = exclusive;
    pb[tid * 4 + 1] = exclusive + c0;
    pb[tid * 4 + 2] = exclusive + c0 + c1;
    pb[tid * 4 + 3] = exclusive + c0 + c1 + c2;
    if (tid == 1023) pb[WORDS] = inclusive;   // total valid count
}

// ---------------------------------------------------------------------------
// Kernel 3: sampling. One block (1024 threads) per batch; sample j = thread j.
// Prefix array staged in LDS; binary search (lower_bound on csum >= t) then
// select the k-th set bit within the word. Matches jnp.searchsorted semantics
// including the empty-mask case (pos = HW -> h=512, w=0).
// ---------------------------------------------------------------------------
__global__ __launch_bounds__(1024) void k_sample(const float* __restrict__ rand_u,
                                                 const uint64_t* __restrict__ bits,
                                                 const int* __restrict__ prefix,
                                                 int* __restrict__ out,
                                                 int out_extra) {
    const int b = blockIdx.x;
    const int j = threadIdx.x;     // 0..1023 == sample index

    __shared__ int lp[WORDS + 1];
    const int* pb = prefix + (size_t)b * (WORDS + 1);
    for (int i = j; i <= WORDS; i += 1024) lp[i] = pb[i];
    __syncthreads();

    const int total = lp[WORDS];
    const int cnt   = total > 0 ? total : 1;

    const float u = rand_u[b * NUM + j];
    int r = (int)(u * (float)cnt);        // trunc toward zero, matches astype(int32)
    if (r > cnt - 1) r = cnt - 1;
    const int t = r + 1;                  // rank target, 1-indexed

    int h, wc;
    if (total == 0) {
        // searchsorted over all-zero csum returns HW -> h = HW/W = 512, w = 0
        h = HH; wc = 0;
    } else {
        // first index i in [1, WORDS] with lp[i] >= t; word = i-1
        int lo = 0, hi = WORDS;           // invariant: lp[lo] < t <= lp[hi]
        while (hi - lo > 1) {
            int mid = (lo + hi) >> 1;
            if (lp[mid] < t) lo = mid; else hi = mid;
        }
        const int w = lo;
        int k = t - lp[w];                // k-th set bit (1-indexed) in word w
        uint64_t v = bits[(size_t)b * WORDS + w];
        int pos = 0;
        #pragma unroll
        for (int sh = 32; sh >= 1; sh >>= 1) {
            int c = __popcll(v & ((1ull << sh) - 1ull));
            if (k > c) { k -= c; v >>= sh; pos += sh; }
        }
        const int pix = w * 64 + pos;
        h  = pix >> 9;          // / W
        wc = pix & (WW - 1);    // % W
    }

    const int o = (b * NUM + j) * 2;
    out[o + 0] = h;
    out[o + 1] = wc;

    // Trailing scalar outputs (H, W) = (512, 512)
    if (b == 0 && j < out_extra) out[BB * NUM * 2 + j] = 512;
}

extern "C" void kernel_launch(void* const* d_in, const int* in_sizes, int n_in,
                              void* d_out, int out_size, void* d_ws, size_t ws_size,
                              hipStream_t stream) {
    const float* ior    = (const float*)d_in[0];   // [64,4,512,512] f32
    const float* rand_u = (const float*)d_in[1];   // [64,1024] f32
    int* out = (int*)d_out;

    // Workspace layout: bits (2 MB, 8B aligned) then prefix (~1.05 MB)
    uint64_t* bits = (uint64_t*)d_ws;
    int* prefix = (int*)((char*)d_ws + (size_t)BB * WORDS * sizeof(uint64_t));

    int out_extra = out_size - BB * NUM * 2;
    if (out_extra < 0) out_extra = 0;

    k_bits<<<BB * 256, 256, 0, stream>>>(ior, bits);
    k_scan<<<BB, 1024, 0, stream>>>(bits, prefix);
    k_sample<<<BB, 1024, 0, stream>>>(rand_u, bits, prefix, out, out_extra);
}

// Round 2
// 354.295 us; speedup vs baseline: 1.0114x; 1.0114x over previous
//
#include <hip/hip_runtime.h>
#include <stdint.h>

// Problem constants (fixed by setup_inputs)
#define BB    64
#define NN    4
#define HH    512
#define WW    512
#define HWPIX (HH * WW)        // 262144 pixels per batch
#define WORDS (HWPIX / 64)     // 4096 uint64 words per batch
#define NUM   1024             // samples per batch

// ---------------------------------------------------------------------------
// Kernel 1: valid = (sum over N of mask) > 0.5, packed into uint64 bitmask.
// 256 threads/block, 4 pixels/thread (float4 loads), 256 blocks per batch.
// Sum order is sequential ((m0+m1)+m2)+m3 to match the reference reduction.
// This kernel is at the read floor: 256 MB of mask data, read exactly once.
// ---------------------------------------------------------------------------
__global__ __launch_bounds__(256) void k_bits(const float* __restrict__ m,
                                              uint64_t* __restrict__ bits) {
    const int bid   = blockIdx.x;
    const int b     = bid >> 8;        // 256 blocks per batch
    const int chunk = bid & 255;       // 1024 pixels per block
    const int tid   = threadIdx.x;     // 0..255
    const int base  = chunk * 1024 + tid * 4;   // pixel index within batch

    const float* p = m + (size_t)b * (NN * HWPIX) + base;
    float4 v0 = *(const float4*)(p);
    float4 v1 = *(const float4*)(p + HWPIX);
    float4 v2 = *(const float4*)(p + 2 * HWPIX);
    float4 v3 = *(const float4*)(p + 3 * HWPIX);

    float s0 = ((v0.x + v1.x) + v2.x) + v3.x;
    float s1 = ((v0.y + v1.y) + v2.y) + v3.y;
    float s2 = ((v0.z + v1.z) + v2.z) + v3.z;
    float s3 = ((v0.w + v1.w) + v2.w) + v3.w;

    unsigned nib = (s0 > 0.5f ? 1u : 0u) | (s1 > 0.5f ? 2u : 0u) |
                   (s2 > 0.5f ? 4u : 0u) | (s3 > 0.5f ? 8u : 0u);

    const int lane = tid & 63;
    // Pixel handled by lane l, sub-pixel k maps to word (chunk*16 + wave*4 + l/16),
    // bit 4*(l&15)+k. Pack nibble, OR-combine across each 16-lane group.
    unsigned long long wv = (unsigned long long)nib << (4 * (lane & 15));
    wv |= __shfl_xor(wv, 1);
    wv |= __shfl_xor(wv, 2);
    wv |= __shfl_xor(wv, 4);
    wv |= __shfl_xor(wv, 8);
    if ((lane & 15) == 0) {
        const int widx = chunk * 16 + (tid >> 6) * 4 + (lane >> 4);
        bits[(size_t)b * WORDS + widx] = wv;
    }
}

// ---------------------------------------------------------------------------
// Kernel 2 (fused scan + sample): one 1024-thread block per batch.
// Loads the 4096 bit-words (32 KB) into LDS, popcount + Hillis-Steele scan
// to build the per-word exclusive prefix entirely in LDS, then each thread
// handles one sample: binary search over the prefix, k-th-set-bit select
// from the LDS word copy. No global prefix array at all.
// Matches jnp.searchsorted semantics including empty-mask (pos=HW -> 512,0).
// ---------------------------------------------------------------------------
__global__ __launch_bounds__(1024) void k_scan_sample(
        const float* __restrict__ rand_u,
        const uint64_t* __restrict__ bits,
        int* __restrict__ out,
        int out_extra) {
    const int b   = blockIdx.x;
    const int tid = threadIdx.x;          // 0..1023; also the sample index

    __shared__ uint64_t wlds[WORDS];      // 32 KB: the batch's bit-words
    __shared__ int      sc[1024];         // scan workspace (per-thread totals)
    __shared__ int      lp[WORDS + 1];    // 16.4 KB: exclusive per-word prefix

    // --- load 4 consecutive words/thread (32 B, coalesced) ---
    const uint64_t* wb = bits + (size_t)b * WORDS;
    ulonglong2 va = *(const ulonglong2*)(wb + tid * 4);
    ulonglong2 vb = *(const ulonglong2*)(wb + tid * 4 + 2);
    wlds[tid * 4 + 0] = va.x;
    wlds[tid * 4 + 1] = va.y;
    wlds[tid * 4 + 2] = vb.x;
    wlds[tid * 4 + 3] = vb.y;
    int c0 = __popcll(va.x), c1 = __popcll(va.y);
    int c2 = __popcll(vb.x), c3 = __popcll(vb.y);
    int tot = c0 + c1 + c2 + c3;
    sc[tid] = tot;
    __syncthreads();

    // --- Hillis-Steele inclusive scan over 1024 per-thread totals ---
    for (int off = 1; off < 1024; off <<= 1) {
        int v = (tid >= off) ? sc[tid - off] : 0;
        __syncthreads();
        sc[tid] += v;
        __syncthreads();
    }
    const int inclusive = sc[tid];
    const int exclusive = inclusive - tot;

    lp[tid * 4 + 0] = exclusive;
    lp[tid * 4 + 1] = exclusive + c0;
    lp[tid * 4 + 2] = exclusive + c0 + c1;
    lp[tid * 4 + 3] = exclusive + c0 + c1 + c2;
    if (tid == 1023) lp[WORDS] = inclusive;   // total valid count
    __syncthreads();

    // --- sample: thread tid == sample j ---
    const int total = lp[WORDS];
    const int cnt   = total > 0 ? total : 1;

    const float u = rand_u[b * NUM + tid];
    int r = (int)(u * (float)cnt);        // trunc toward zero == astype(int32)
    if (r > cnt - 1) r = cnt - 1;
    const int t = r + 1;                  // rank target, 1-indexed

    int h, wc;
    if (total == 0) {
        // searchsorted over all-zero csum returns HW -> h = HW/W = 512, w = 0
        h = HH; wc = 0;
    } else {
        // first index i in [1, WORDS] with lp[i] >= t; word = i-1
        int lo = 0, hi = WORDS;           // invariant: lp[lo] < t <= lp[hi]
        while (hi - lo > 1) {
            int mid = (lo + hi) >> 1;
            if (lp[mid] < t) lo = mid; else hi = mid;
        }
        const int w = lo;
        int k = t - lp[w];                // k-th set bit (1-indexed) in word w
        uint64_t v = wlds[w];
        int pos = 0;
        #pragma unroll
        for (int sh = 32; sh >= 1; sh >>= 1) {
            int c = __popcll(v & ((1ull << sh) - 1ull));
            if (k > c) { k -= c; v >>= sh; pos += sh; }
        }
        const int pix = w * 64 + pos;
        h  = pix >> 9;          // / W
        wc = pix & (WW - 1);    // % W
    }

    const int o = (b * NUM + tid) * 2;
    out[o + 0] = h;
    out[o + 1] = wc;

    // Trailing scalar outputs (H, W) = (512, 512)
    if (b == 0 && tid < out_extra) out[BB * NUM * 2 + tid] = 512;
}

extern "C" void kernel_launch(void* const* d_in, const int* in_sizes, int n_in,
                              void* d_out, int out_size, void* d_ws, size_t ws_size,
                              hipStream_t stream) {
    const float* ior    = (const float*)d_in[0];   // [64,4,512,512] f32
    const float* rand_u = (const float*)d_in[1];   // [64,1024] f32
    int* out = (int*)d_out;

    // Workspace: bits only (2 MB, 8B aligned)
    uint64_t* bits = (uint64_t*)d_ws;

    int out_extra = out_size - BB * NUM * 2;
    if (out_extra < 0) out_extra = 0;

    k_bits<<<BB * 256, 256, 0, stream>>>(ior, bits);
    k_scan_sample<<<BB, 1024, 0, stream>>>(rand_u, bits, out, out_extra);
}